// Round 7
// baseline (210.591 us; speedup 1.0000x reference)
//
#include <hip/hip_runtime.h>

#define GRID_N 112
#define O_MAX 48
#define HW_N (GRID_N * GRID_N)   // 12544
#define NT 448                   // 7 wave-private waves; wave w owns row strip w
#define NB 2                     // batches per block: grid 1024 (tests WG-rate cap)

typedef _Float16 half8 __attribute__((ext_vector_type(8)));
typedef float    f32x4 __attribute__((ext_vector_type(4)));
typedef float    f32x2 __attribute__((ext_vector_type(2)));

constexpr float INV = 1.0f / (2.0f * 5.0f * 5.0f);  // SIGMA = 5.0

// ---- phase helpers: all loops fully unrolled -> static indexing, registers only
__device__ __forceinline__ void gather_oc(const float* __restrict__ ob, int n, int quad,
                                          f32x2* oc0, f32x2* oc1) {
    #pragma unroll
    for (int j = 0; j < 8; ++j) {
        int k = quad * 8 + j;                   // k in [0,32)
        oc0[j] = *(const f32x2*)&ob[k * 2];     // (y,x), always in-bounds
        bool g = (k + 32 < n);
        f32x2 z = {0.f, 0.f};
        oc1[j] = g ? *(const f32x2*)&ob[(k + 32) * 2] : z;
    }
}

__device__ __forceinline__ void load_masks(const int* __restrict__ rm, int h0, int m,
                                           int (*mk)[4]) {
    #pragma unroll
    for (int i = 0; i < 7; ++i) {
        int base = h0 * GRID_N + i * 16 + m;
        #pragma unroll
        for (int r = 0; r < 4; ++r)
            mk[i][r] = rm[base + r * GRID_N];
    }
}

__device__ __forceinline__ void build_a(int n, int ksteps, float fh, float xl, int quad,
                                        const f32x2* oc0, const f32x2* oc1,
                                        half8& a0, half8& a1) {
    #pragma unroll
    for (int j = 0; j < 8; ++j) {
        int k = quad * 8 + j;
        float val = 0.f;
        if (k <= n) {
            float cx = (k < n) ? oc0[j][1] : xl;
            float s  = (k < n) ? -0.5f  : 0.5f;
            float d  = fh - cx;
            val = s * __expf(-d * d * INV);
        }
        a0[j] = (_Float16)val;
    }
    if (ksteps == 2) {
        #pragma unroll
        for (int j = 0; j < 8; ++j) {
            int k = quad * 8 + j + 32;
            float val = 0.f;
            if (k <= n) {
                float cx = (k < n) ? oc1[j][1] : xl;
                float s  = (k < n) ? -0.5f  : 0.5f;
                float d  = fh - cx;
                val = s * __expf(-d * d * INV);
            }
            a1[j] = (_Float16)val;
        }
    }
}

__device__ __forceinline__ void sweep(int n, int ksteps, float yl, int m, int quad, int h0,
                                      const f32x2* oc0, const f32x2* oc1,
                                      half8 a0, half8 a1, const int (*mk)[4],
                                      float* __restrict__ op) {
    #pragma unroll
    for (int tw = 0; tw < 7; ++tw) {
        const float fw = (float)(tw * 16 + m);
        half8 b0;
        #pragma unroll
        for (int j = 0; j < 8; ++j) {
            int k = quad * 8 + j;
            float val = 0.f;
            if (k <= n) {
                float cy = (k < n) ? oc0[j][0] : yl;
                float d  = fw - cy;
                val = __expf(-d * d * INV);
            }
            b0[j] = (_Float16)val;
        }
        f32x4 acc = {0.f, 0.f, 0.f, 0.f};
        acc = __builtin_amdgcn_mfma_f32_16x16x32_f16(a0, b0, acc, 0, 0, 0);
        if (ksteps == 2) {
            half8 b1;
            #pragma unroll
            for (int j = 0; j < 8; ++j) {
                int k = quad * 8 + j + 32;
                float val = 0.f;
                if (k <= n) {
                    float cy = (k < n) ? oc1[j][0] : yl;
                    float d  = fw - cy;
                    val = __expf(-d * d * INV);
                }
                b1[j] = (_Float16)val;
            }
            acc = __builtin_amdgcn_mfma_f32_16x16x32_f16(a1, b1, acc, 0, 0, 0);
        }
        const int w0 = tw * 16 + m;
        #pragma unroll
        for (int r = 0; r < 4; ++r) {
            float v = 0.5f + acc[r];
            v = (mk[tw][r] == 0) ? 0.f : v;
            op[(h0 + r) * GRID_N + w0] = v;
        }
    }
}

// Two batches per block, software-pipelined INSIDE each wave (no LDS, no
// barriers, no inter-wave coupling): b1's gathers overlap b0's exp chain,
// b1's mask loads overlap b1's A-build; the vmcnt queue never drains until
// the end. Halves the workgroup count (tests the ~30 WG/us chip-wide
// launch-rate cap that retrodicts all six flat ~68 us results).
__global__ __launch_bounds__(NT) void goalmap_kernel(
    const float* __restrict__ xL, const float* __restrict__ yL,
    const float* __restrict__ obj_list, const int* __restrict__ obj_num,
    const int* __restrict__ road_mask, float* __restrict__ out, int B)
{
    const int tid  = threadIdx.x;
    const int lane = tid & 63;
    const int wid  = tid >> 6;                  // 0..6: row strip
    const int m    = lane & 15;
    const int quad = lane >> 4;
    const int h0   = wid * 16 + quad * 4;       // C/D row base
    const float fh = (float)(wid * 16 + m);

    const int b0 = blockIdx.x * NB;
    const int b1 = b0 + 1;

    // scalar params (s_load path, off the vmcnt FIFO)
    const int   n0  = obj_num[b0];
    const float xl0 = xL[b0], yl0 = yL[b0];
    const int ksteps0 = (n0 >= 32) ? 2 : 1;

    // ---- (1) b0 obj gathers first in the vmcnt FIFO
    f32x2 oc0_b0[8], oc1_b0[8];
    gather_oc(obj_list + (size_t)b0 * (O_MAX * 2), n0, quad, oc0_b0, oc1_b0);
    __builtin_amdgcn_sched_barrier(0);

    // ---- (2) b0 mask loads
    int mk0[7][4];
    load_masks(road_mask + (size_t)b0 * HW_N, h0, m, mk0);
    __builtin_amdgcn_sched_barrier(0);

    // ---- (3) b1 obj gathers issued BEFORE b0's exp chain consumes oc_b0
    f32x2 oc0_b1[8], oc1_b1[8];
    int n1 = 0; float xl1 = 0.f, yl1 = 0.f;
    const bool has_b1 = (b1 < B);
    if (has_b1) {
        n1 = obj_num[b1]; xl1 = xL[b1]; yl1 = yL[b1];
        gather_oc(obj_list + (size_t)b1 * (O_MAX * 2), n1, quad, oc0_b1, oc1_b1);
    }
    __builtin_amdgcn_sched_barrier(0);

    // ---- (4) b0 A-fragments (waits oc_b0 only; masks + oc_b1 stay in flight)
    half8 a0_b0, a1_b0;
    build_a(n0, ksteps0, fh, xl0, quad, oc0_b0, oc1_b0, a0_b0, a1_b0);
    __builtin_amdgcn_sched_barrier(0);

    // ---- (5) b0 sweep: exps + MFMA + mask select + stores
    sweep(n0, ksteps0, yl0, m, quad, h0, oc0_b0, oc1_b0, a0_b0, a1_b0, mk0,
          out + (size_t)b0 * HW_N);
    __builtin_amdgcn_sched_barrier(0);

    if (has_b1) {
        const int ksteps1 = (n1 >= 32) ? 2 : 1;

        // ---- (6) b1 mask loads (overlap b1's exp chains below)
        int mk1[7][4];
        load_masks(road_mask + (size_t)b1 * HW_N, h0, m, mk1);
        __builtin_amdgcn_sched_barrier(0);

        // ---- (7) b1 A-fragments (oc_b1 landed during b0's sweep)
        half8 a0_b1, a1_b1;
        build_a(n1, ksteps1, fh, xl1, quad, oc0_b1, oc1_b1, a0_b1, a1_b1);
        __builtin_amdgcn_sched_barrier(0);

        // ---- (8) b1 sweep
        sweep(n1, ksteps1, yl1, m, quad, h0, oc0_b1, oc1_b1, a0_b1, a1_b1, mk1,
              out + (size_t)b1 * HW_N);
    }
}

extern "C" void kernel_launch(void* const* d_in, const int* in_sizes, int n_in,
                              void* d_out, int out_size, void* d_ws, size_t ws_size,
                              hipStream_t stream) {
    const float* xL        = (const float*)d_in[0];
    const float* yL        = (const float*)d_in[1];
    const float* obj_list  = (const float*)d_in[2];
    const int*   obj_num   = (const int*)d_in[3];
    const int*   road_mask = (const int*)d_in[4];
    float*       out       = (float*)d_out;
    const int B = in_sizes[0];  // 2048

    const int grid = (B + NB - 1) / NB;  // 1024
    goalmap_kernel<<<grid, NT, 0, stream>>>(xL, yL, obj_list, obj_num, road_mask, out, B);
}